// Round 8
// baseline (219.800 us; speedup 1.0000x reference)
//
#include <hip/hip_runtime.h>
#include <math.h>

static constexpr int B_  = 2;
static constexpr int S_  = 2048;
static constexpr int E_  = 1024;
static constexpr int NH_ = 4;
static constexpr int HD_ = 256;
static constexpr int BH_ = B_ * NH_;

typedef __attribute__((ext_vector_type(8))) _Float16 half8;
typedef __attribute__((ext_vector_type(4))) float    f32x4;
typedef __attribute__((ext_vector_type(4))) _Float16 half4v;

// Fragment-major layouts (written by prep, read by mlstm as coalesced 1 KB lines):
//  Q/K per bh: frag(rb16 = s>>4, kk = d>>5) at ((rb16*8 + kk)*512) halfs;
//              lane l = (s&15) + (((d&31)>>3)<<4) holds halfs j = d&7.
//  V^T per bh: frag(ktile = s>>6, dblk = d>>4, kb = (s&63)>>5) at
//              (((ktile*16 + dblk)*2 + kb)*512) halfs; lane l = (d&15) + (((s&31)>>3)<<4), j = s&7.

__device__ __forceinline__ int wofs(int e) { return (e << 4) ^ ((e & 0x38) << 1); }

// ---------------- Kernel 1: gates + fp16 Q/K (frag-major) + V frag-transpose (unchanged) ----------------
__global__ __launch_bounds__(1024) void prep_kernel(
    const float* __restrict__ q, const float* __restrict__ k, const float* __restrict__ v,
    const float* __restrict__ igk, const float* __restrict__ igb,
    const float* __restrict__ fgk, const float* __restrict__ fgb,
    float* __restrict__ ig_out, float* __restrict__ fg_out,
    _Float16* __restrict__ Qh, _Float16* __restrict__ Kh, _Float16* __restrict__ Vt)
{
    __shared__ __align__(16) char PSM[98304];
    char* wiB = PSM;            // 48 KB, swizzled float4 per element
    char* wfB = PSM + 49152;

    const int t = threadIdx.x;
    #pragma unroll
    for (int i = 0; i < 3; ++i) {
        int e = t + 1024 * i;
        *(float4*)(wiB + wofs(e)) = ((const float4*)igk)[e];
        *(float4*)(wfB + wofs(e)) = ((const float4*)fgk)[e];
    }
    __syncthreads();

    const int wave = t >> 6;
    const int l    = t & 63;
    const int bs   = blockIdx.x * 16 + wave;     // b*S + s
    const int b = bs >> 11, s = bs & (S_ - 1);
    const float* qrow = q + (size_t)bs * E_;
    const float* krow = k + (size_t)bs * E_;
    const float* vrow = v + (size_t)bs * E_;

    float accI[4] = {0.f,0.f,0.f,0.f}, accF[4] = {0.f,0.f,0.f,0.f};
    #pragma unroll
    for (int j = 0; j < 12; ++j) {
        const int e4 = l * 4 + 256 * j;          // 4 consecutive elements of gate_in
        float4 g4;
        if (j < 4)       g4 = *(const float4*)(qrow + e4);
        else if (j < 8)  g4 = *(const float4*)(krow + (e4 - E_));
        else             g4 = *(const float4*)(vrow + (e4 - 2 * E_));
        const float ge[4] = {g4.x, g4.y, g4.z, g4.w};
        if (j < 4) {
            const int d = e4 & 255, hh = e4 >> 8;
            const int idx = ((s >> 4) * 8 + (d >> 5)) * 512
                          + (s & 15) * 8 + (((d & 31) >> 3) << 7) + (d & 7);
            half4v st;
            st.x = (_Float16)(ge[0] * 0.0625f); st.y = (_Float16)(ge[1] * 0.0625f);
            st.z = (_Float16)(ge[2] * 0.0625f); st.w = (_Float16)(ge[3] * 0.0625f);
            *(half4v*)(Qh + ((size_t)(b * NH_ + hh)) * (S_ * HD_) + idx) = st;
        } else if (j < 8) {
            const int e2 = e4 - E_;
            const int d = e2 & 255, hh = e2 >> 8;
            const int idx = ((s >> 4) * 8 + (d >> 5)) * 512
                          + (s & 15) * 8 + (((d & 31) >> 3) << 7) + (d & 7);
            half4v st;
            st.x = (_Float16)ge[0]; st.y = (_Float16)ge[1];
            st.z = (_Float16)ge[2]; st.w = (_Float16)ge[3];
            *(half4v*)(Kh + ((size_t)(b * NH_ + hh)) * (S_ * HD_) + idx) = st;
        }
        #pragma unroll
        for (int i = 0; i < 4; ++i) {
            float4 wiv = *(const float4*)(wiB + wofs(e4 + i));
            float4 wfv = *(const float4*)(wfB + wofs(e4 + i));
            accI[0] = fmaf(ge[i], wiv.x, accI[0]); accI[1] = fmaf(ge[i], wiv.y, accI[1]);
            accI[2] = fmaf(ge[i], wiv.z, accI[2]); accI[3] = fmaf(ge[i], wiv.w, accI[3]);
            accF[0] = fmaf(ge[i], wfv.x, accF[0]); accF[1] = fmaf(ge[i], wfv.y, accF[1]);
            accF[2] = fmaf(ge[i], wfv.z, accF[2]); accF[3] = fmaf(ge[i], wfv.w, accF[3]);
        }
    }
    #pragma unroll
    for (int m = 1; m < 64; m <<= 1) {
        #pragma unroll
        for (int h = 0; h < 4; ++h) {
            accI[h] += __shfl_xor(accI[h], m);
            accF[h] += __shfl_xor(accF[h], m);
        }
    }
    if (l == 0) {
        #pragma unroll
        for (int h = 0; h < 4; ++h) {
            ig_out[((size_t)(b * NH_ + h)) * S_ + s] = accI[h] + igb[h];
            fg_out[((size_t)(b * NH_ + h)) * S_ + s] = accF[h] + fgb[h];
        }
    }

    __syncthreads();    // all weight reads done; reuse LDS for V transpose
    {
        float (*tile)[65] = (float(*)[65])(PSM + (t >> 8) * 16640);
        const int tid = t & 255;
        const int m  = blockIdx.x * 4 + (t >> 8);    // 0..1023 tile jobs
        const int bh = m & 7;
        const int sb = (m >> 3) & 31;                // ktile
        const int db = m >> 8;                       // d block of 64
        const int bb = bh >> 2, hh = bh & 3;
        const int j4 = (tid & 15) * 4;
        const int i0 = tid >> 4;
        const float* src = v + ((size_t)(bb * S_ + sb * 64)) * E_ + hh * HD_ + db * 64;
        #pragma unroll
        for (int p = 0; p < 4; ++p) {
            int i = i0 + p * 16;
            float4 val = *(const float4*)(src + (size_t)i * E_ + j4);
            tile[i][j4] = val.x; tile[i][j4+1] = val.y; tile[i][j4+2] = val.z; tile[i][j4+3] = val.w;
        }
        __syncthreads();
        const int ll = tid & 63;
        const int sw_ = tid >> 6;
        _Float16* dstb = Vt + (size_t)bh * (S_ * HD_);
        #pragma unroll
        for (int kb = 0; kb < 2; ++kb) {
            half8 pk;
            #pragma unroll
            for (int jj = 0; jj < 8; ++jj)
                pk[jj] = (_Float16)tile[kb * 32 + (ll >> 4) * 8 + jj][sw_ * 16 + (ll & 15)];
            *(half8*)(dstb + ((size_t)((sb * 16 + db * 4 + sw_) * 2 + kb)) * 512 + ll * 8) = pk;
        }
    }
}

// ---------------- Kernel 2 (R8): producer/consumer wave specialization, 16 waves ----------------
// R7 post-mortem: 1 block/CU = 2 waves/SIMD; per-tile 5.7K cy vs ~2K of work = TLP-starved
// latency. Can't widen with the old structure: qf+kf+vf = 128 MFMA-operand VGPRs per wave.
// R8: 1024 threads. Waves 0-7 = QK producers (kf regs, Q from LDS, fixup, P write, rowsums);
// waves 8-15 = PV consumers (vf regs + acc, P from LDS, out stores). Roles never need all
// operand sets -> fits the forced 128-reg cap of (1024,4) -> 4 waves/SIMD. QK(i) || PV(i-1)
// overlap ACROSS waves (R5's merge without the liveness bomb). K/V traffic unchanged (zero
// duplication). Non-temporal out stores keep K/V resident in the 4 MB XCD L2.
static constexpr int OFF_PB  = 16384;                  // qlds [2][8 kk][64 lane][16 B] at 0
static constexpr int OFF_AMM = OFF_PB + 16384;         // P dbuf [2][32 rows][256 B]
static constexpr int OFF_G   = OFF_AMM + S_ * 4;
static constexpr int OFF_M   = OFF_G + S_ * 4;
static constexpr int OFF_RS  = OFF_M + S_ * 4;         // [8][32] floats
static constexpr int OFF_SS  = OFF_RS + 1024;
static constexpr int OFF_WR  = OFF_SS + 1024;          // [16]+[16] floats
static constexpr int SMB     = OFF_WR + 128;

#define QK_BODY(ii)                                                           \
{                                                                             \
    const int ii_ = (ii);                                                     \
    f32x4 s0 = (f32x4){0.f,0.f,0.f,0.f}, s1 = (f32x4){0.f,0.f,0.f,0.f};      \
    __builtin_amdgcn_s_setprio(1);                                            \
    _Pragma("unroll")                                                         \
    for (int kk = 0; kk < 8; ++kk) {                                          \
        half8 q0 = *(const half8*)(qlds + (kk * 64 + l) * 16);                \
        half8 q1 = *(const half8*)(qlds + 8192 + (kk * 64 + l) * 16);         \
        s0 = __builtin_amdgcn_mfma_f32_16x16x32_f16(kf[kk], q0, s0, 0, 0, 0); \
        s1 = __builtin_amdgcn_mfma_f32_16x16x32_f16(kf[kk], q1, s1, 0, 0, 0); \
    }                                                                         \
    __builtin_amdgcn_s_setprio(0);                                            \
    if (ii_ + 1 < Tt) {     /* refill kf for next tile; in flight across barrier */ \
        const _Float16* kb_ = Kp + ((size_t)((ii_ + 1) * 8 + wp) * 8) * 512 + l * 8; \
        _Pragma("unroll")                                                     \
        for (int kk = 0; kk < 8; ++kk) kf[kk] = *(const half8*)(kb_ + kk * 512); \
    }                                                                         \
    float4 gv4 = *(const float4*)(sG + ii_ * 128 + wp * 16 + quad * 4);       \
    const float gvv[4] = {gv4.x, gv4.y, gv4.z, gv4.w};                        \
    char* pbC = Pb + (ii_ & 1) * 8192;                                        \
    half4v h0, h1;                                                            \
    const bool mask_ = (ii_ == Tt - 1);                                       \
    _Pragma("unroll")                                                         \
    for (int rr = 0; rr < 4; ++rr) {                                          \
        float p0 = s0[rr] * __builtin_amdgcn_exp2f(amM0 + gvv[rr]);           \
        float p1 = s1[rr] * __builtin_amdgcn_exp2f(amM1 + gvv[rr]);           \
        if (mask_) {                                                          \
            const int gc = ii_ * 128 + wp * 16 + quad * 4 + rr;               \
            p0 = (gc <= rowbase + col) ? p0 : 0.f;                            \
            p1 = (gc <= rowbase + 16 + col) ? p1 : 0.f;                       \
        }                                                                     \
        rs0 += p0; rs1 += p1;                                                 \
        h0[rr] = (_Float16)p0; h1[rr] = (_Float16)p1;                         \
    }                                                                         \
    const int wb = (wp * 32 + quad * 8) ^ ((col & 7) << 4);                   \
    *(half4v*)(pbC + col * 256 + wb) = h0;                                    \
    *(half4v*)(pbC + (16 + col) * 256 + wb) = h1;                             \
}

#define ISSV(jj)                                                              \
{                                                                             \
    const _Float16* vb_ = Vtp + (size_t)(jj) * 32768 + l * 8;                 \
    _Pragma("unroll")                                                         \
    for (int dn = 0; dn < 2; ++dn) {                                          \
        _Pragma("unroll")                                                     \
        for (int k0 = 0; k0 < 4; ++k0)                                        \
            vf[dn * 4 + k0] = *(const half8*)(vb_                             \
                + (((k0 >> 1) * 16 + wp * 2 + dn) * 2 + (k0 & 1)) * 512);     \
    }                                                                         \
}

#define PV_BODY(jj)                                                           \
{                                                                             \
    const char* pbC = Pb + ((jj) & 1) * 8192;                                 \
    const int sw2 = (col & 7) << 4;                                           \
    __builtin_amdgcn_s_setprio(1);                                            \
    _Pragma("unroll")                                                         \
    for (int rsub = 0; rsub < 2; ++rsub) {                                    \
        const char* base = pbC + (rsub * 16 + col) * 256;                     \
        half8 af[4];                                                          \
        _Pragma("unroll")                                                     \
        for (int k0 = 0; k0 < 4; ++k0)                                        \
            af[k0] = *(const half8*)(base + ((k0 * 64 + quad * 16) ^ sw2));   \
        _Pragma("unroll")                                                     \
        for (int k0 = 0; k0 < 4; ++k0) {                                      \
            acc[rsub * 2 + 0] = __builtin_amdgcn_mfma_f32_16x16x32_f16(af[k0], vf[k0],     acc[rsub * 2 + 0], 0, 0, 0); \
            acc[rsub * 2 + 1] = __builtin_amdgcn_mfma_f32_16x16x32_f16(af[k0], vf[4 + k0], acc[rsub * 2 + 1], 0, 0, 0); \
        }                                                                     \
    }                                                                         \
    __builtin_amdgcn_s_setprio(0);                                            \
}

#define LGKM_BARRIER() do {                                                   \
    asm volatile("s_waitcnt lgkmcnt(0)" ::: "memory");                        \
    __builtin_amdgcn_s_barrier();                                             \
} while (0)

__global__ __launch_bounds__(1024, 4) void mlstm_kernel(
    const _Float16* __restrict__ Qh, const _Float16* __restrict__ Kh,
    const _Float16* __restrict__ Vt,
    const float* __restrict__ ig, const float* __restrict__ fg,
    const float* __restrict__ rms_scale, float* __restrict__ out)
{
    __shared__ __align__(16) char SMEM[SMB];
    char*  qlds  = SMEM;                             // [2 rh][8 kk][64 lane][16 B]
    char*  Pb    = SMEM + OFF_PB;                    // [2][32][256 B] halfs, swizzled
    float* sAmM  = (float*)(SMEM + OFF_AMM);         // [S]  (A-M)*log2e
    float* sG    = (float*)(SMEM + OFF_G);           // [S]  g*log2e
    float* sM    = (float*)(SMEM + OFF_M);           // [S]  M
    float* rsumP = (float*)(SMEM + OFF_RS);          // [8][32]
    float* ssP   = (float*)(SMEM + OFF_SS);          // [8][32]
    float* wred  = (float*)(SMEM + OFF_WR);          // [16]
    float* wred2 = wred + 16;                        // [16]

    const int z  = blockIdx.x;
    const int bh = z & 7;                 // one head per XCD
    const int u  = z >> 3;                // 0..31; block owns row-blocks {u, 63-u}
    const int b  = bh >> 2, h = bh & 3;
    const int t  = threadIdx.x;
    const int w  = t >> 6;                // 0..15
    const int l  = t & 63;
    const int col  = l & 15;
    const int quad = l >> 4;
    const bool isQK = (w < 8);
    const int wp = w & 7;                 // QK: k-group; PV: d-slice index
    constexpr float LOG2E = 1.4426950408889634f;

    // ---- scan prologue: 1024 threads x 2 elems, wave-level shfl scans ----
    {
        const float* fgp = fg + (size_t)bh * S_;
        const float* igp = ig + (size_t)bh * S_;
        float2 fx = *(const float2*)(fgp + t * 2);
        float2 ix = *(const float2*)(igp + t * 2);
        float xi[2] = {fx.x, fx.y};
        float gi[2] = {ix.x, ix.y};
        float ls[2];
        float run = 0.f;
        #pragma unroll
        for (int i = 0; i < 2; ++i) {
            float x = xi[i];
            float lg = (x >= 0.f) ? -log1pf(expf(-x)) : (x - log1pf(expf(x)));
            run += lg;
            ls[i] = run;
        }
        const float own = run;
        #pragma unroll
        for (int m = 1; m < 64; m <<= 1) {
            float o = __shfl_up(run, m);
            if (l >= m) run += o;
        }
        if (l == 63) wred[w] = run;
        __syncthreads();
        float wpre = 0.f;
        for (int ww = 0; ww < w; ++ww) wpre += wred[ww];
        const float exclT = wpre + run - own;
        float A[2], g[2], gm[2];
        float rmax = -__builtin_inff();
        #pragma unroll
        for (int i = 0; i < 2; ++i) {
            A[i] = exclT + ls[i];
            g[i] = gi[i] - A[i];
            rmax = fmaxf(rmax, g[i]);
            gm[i] = rmax;
        }
        float sm = rmax;
        #pragma unroll
        for (int m = 1; m < 64; m <<= 1) {
            float o = __shfl_up(sm, m);
            if (l >= m) sm = fmaxf(sm, o);
        }
        if (l == 63) wred2[w] = sm;
        __syncthreads();
        float exm = -__builtin_inff();
        for (int ww = 0; ww < w; ++ww) exm = fmaxf(exm, wred2[ww]);
        float up = __shfl_up(sm, 1);
        if (l > 0) exm = fmaxf(exm, up);
        #pragma unroll
        for (int i = 0; i < 2; ++i) {
            float cm = fmaxf(exm, gm[i]);
            float Mi = A[i] + cm;
            sAmM[t * 2 + i] = (A[i] - Mi) * LOG2E;
            sG[t * 2 + i]   = g[i] * LOG2E;
            sM[t * 2 + i]   = Mi;
        }
        __syncthreads();
    }

    const _Float16* Qp  = Qh + (size_t)bh * S_ * HD_;
    const _Float16* Kp  = Kh + (size_t)bh * S_ * HD_;
    const _Float16* Vtp = Vt + (size_t)bh * HD_ * S_;

    half8 kf[8], vf[8];

    for (int pass = 0; pass < 2; ++pass) {
        const int rb = pass ? (63 - u) : u;
        const int rowbase = rb * 32;
        const int Tt = (rb >> 2) + 1;          // KVBLK=128 causal tile count

        // stage Q tile (32 rows x 256 d, 16 KB) into LDS; all 1024 threads, 16 B each
        {
            const _Float16* qsrc = Qp + ((size_t)(rb * 16 + (t >> 6))) * 512 + (t & 63) * 8;
            *(half8*)(qlds + t * 16) = *(const half8*)qsrc;
        }
        float amM0 = 0.f, amM1 = 0.f, rs0 = 0.f, rs1 = 0.f;
        f32x4 acc[4];
        if (isQK) {
            const _Float16* kb_ = Kp + ((size_t)(wp * 8)) * 512 + l * 8;
            #pragma unroll
            for (int kk = 0; kk < 8; ++kk)
                kf[kk] = *(const half8*)(kb_ + kk * 512);
            amM0 = sAmM[rowbase + col];
            amM1 = sAmM[rowbase + 16 + col];
        } else {
            #pragma unroll
            for (int i = 0; i < 4; ++i) acc[i] = (f32x4){0.f, 0.f, 0.f, 0.f};
        }
        LGKM_BARRIER();    // qlds staged (kf loads remain in flight)

        // iteration 0: QK tile 0 || PV issues V(0)
        if (isQK) { QK_BODY(0); }
        else      { ISSV(0); }
        LGKM_BARRIER();
        // iterations i: QK tile i (if < Tt) || PV tile i-1, then V(i) prefetch
        for (int i = 1; ; ++i) {
            if (isQK) {
                if (i < Tt) QK_BODY(i);
            } else {
                PV_BODY(i - 1);
                if (i < Tt) ISSV(i);
            }
            LGKM_BARRIER();
            if (i >= Tt) break;
        }

        // ---- epilogue ----
        if (isQK) {
            rs0 += __shfl_xor(rs0, 16); rs0 += __shfl_xor(rs0, 32);
            rs1 += __shfl_xor(rs1, 16); rs1 += __shfl_xor(rs1, 32);
            if (quad == 0) {
                rsumP[wp * 32 + col]      = rs0;
                rsumP[wp * 32 + 16 + col] = rs1;
            }
        }
        __syncthreads();
        if (!isQK) {
            float inv0[4], inv1[4];
            #pragma unroll
            for (int rr = 0; rr < 4; ++rr) {
                const int r0 = quad * 4 + rr;
                float tot0 = 0.f, tot1 = 0.f;
                #pragma unroll
                for (int ww = 0; ww < 8; ++ww) {
                    tot0 += rsumP[ww * 32 + r0];
                    tot1 += rsumP[ww * 32 + 16 + r0];
                }
                float M0 = sM[rowbase + r0];
                float M1 = sM[rowbase + 16 + r0];
                inv0[rr] = 1.0f / (fmaxf(tot0, __expf(-M0)) + 1e-6f);
                inv1[rr] = 1.0f / (fmaxf(tot1, __expf(-M1)) + 1e-6f);
            }
            float ss0[4] = {0.f,0.f,0.f,0.f}, ss1[4] = {0.f,0.f,0.f,0.f};
            #pragma unroll
            for (int dn = 0; dn < 2; ++dn) {
                #pragma unroll
                for (int rr = 0; rr < 4; ++rr) {
                    float h0 = acc[dn][rr] * inv0[rr];
                    acc[dn][rr] = h0;
                    ss0[rr] = fmaf(h0, h0, ss0[rr]);
                    float h1 = acc[2 + dn][rr] * inv1[rr];
                    acc[2 + dn][rr] = h1;
                    ss1[rr] = fmaf(h1, h1, ss1[rr]);
                }
            }
            #pragma unroll
            for (int m = 1; m < 16; m <<= 1) {
                #pragma unroll
                for (int rr = 0; rr < 4; ++rr) {
                    ss0[rr] += __shfl_xor(ss0[rr], m);
                    ss1[rr] += __shfl_xor(ss1[rr], m);
                }
            }
            if (col == 0) {
                #pragma unroll
                for (int rr = 0; rr < 4; ++rr) {
                    ssP[wp * 32 + quad * 4 + rr]      = ss0[rr];
                    ssP[wp * 32 + 16 + quad * 4 + rr] = ss1[rr];
                }
            }
        }
        __syncthreads();
        if (!isQK) {
            const float rsc0 = 1.f + rms_scale[wp * 32 + col];
            const float rsc1 = 1.f + rms_scale[wp * 32 + 16 + col];
            #pragma unroll
            for (int rr = 0; rr < 4; ++rr) {
                const int r0 = quad * 4 + rr;
                float sst0 = 0.f, sst1 = 0.f;
                #pragma unroll
                for (int ww = 0; ww < 8; ++ww) {
                    sst0 += ssP[ww * 32 + r0];
                    sst1 += ssP[ww * 32 + 16 + r0];
                }
                float rstd0 = rsqrtf(sst0 * (1.0f / HD_) + 1e-6f);
                float rstd1 = rsqrtf(sst1 * (1.0f / HD_) + 1e-6f);
                float* o0 = out + ((size_t)(b * S_ + rowbase + r0)) * E_ + h * HD_ + wp * 32;
                float* o1 = out + ((size_t)(b * S_ + rowbase + 16 + r0)) * E_ + h * HD_ + wp * 32;
                // non-temporal: keep K/V resident in the XCD L2
                __builtin_nontemporal_store(acc[0][rr] * rstd0 * rsc0, o0 + col);
                __builtin_nontemporal_store(acc[1][rr] * rstd0 * rsc1, o0 + 16 + col);
                __builtin_nontemporal_store(acc[2][rr] * rstd1 * rsc0, o1 + col);
                __builtin_nontemporal_store(acc[3][rr] * rstd1 * rsc1, o1 + 16 + col);
            }
        }
        __syncthreads();   // rsumP/ssP/qlds retired before next pass restages
    }
}

extern "C" void kernel_launch(void* const* d_in, const int* in_sizes, int n_in,
                              void* d_out, int out_size, void* d_ws, size_t ws_size,
                              hipStream_t stream) {
    (void)in_sizes; (void)n_in; (void)out_size; (void)ws_size;
    const float* q   = (const float*)d_in[0];
    const float* k   = (const float*)d_in[1];
    const float* v   = (const float*)d_in[2];
    const float* igk = (const float*)d_in[3];
    const float* igb = (const float*)d_in[4];
    const float* fgk = (const float*)d_in[5];
    const float* fgb = (const float*)d_in[6];
    const float* rsc = (const float*)d_in[7];
    float* out = (float*)d_out;

    float* ws  = (float*)d_ws;
    float* ig  = ws;                          // BH*S each
    float* fg  = ws + (size_t)BH_ * S_;
    _Float16* Qh = (_Float16*)(ws + (size_t)2 * BH_ * S_);
    _Float16* Kh = Qh + (size_t)BH_ * S_ * HD_;
    _Float16* Vt = Kh + (size_t)BH_ * S_ * HD_;

    prep_kernel<<<B_ * S_ / 16, 1024, 0, stream>>>(q, k, v, igk, igb, fgk, fgb,
                                                   ig, fg, Qh, Kh, Vt);
    mlstm_kernel<<<BH_ * 32, 1024, 0, stream>>>(Qh, Kh, Vt, ig, fg, rsc, out);
}

// Round 9
// 155.632 us; speedup vs baseline: 1.4123x; 1.4123x over previous
//
#include <hip/hip_runtime.h>
#include <math.h>

static constexpr int B_  = 2;
static constexpr int S_  = 2048;
static constexpr int E_  = 1024;
static constexpr int NH_ = 4;
static constexpr int HD_ = 256;
static constexpr int BH_ = B_ * NH_;

typedef __attribute__((ext_vector_type(8))) _Float16 half8;
typedef __attribute__((ext_vector_type(4))) float    f32x4;
typedef __attribute__((ext_vector_type(4))) _Float16 half4v;

// Fragment-major layouts (written by prep, read by mlstm as coalesced 1 KB lines):
//  Q/K per bh: frag(rb16 = s>>4, kk = d>>5) at ((rb16*8 + kk)*512) halfs;
//              lane l = (s&15) + (((d&31)>>3)<<4) holds halfs j = d&7.
//  V^T per bh: frag(ktile = s>>6, dblk = d>>4, kb = (s&63)>>5) at
//              (((ktile*16 + dblk)*2 + kb)*512) halfs; lane l = (d&15) + (((s&31)>>3)<<4), j = s&7.

__device__ __forceinline__ int wofs(int e) { return (e << 4) ^ ((e & 0x38) << 1); }

// ---------------- Kernel 1: gates + fp16 Q/K (frag-major) + V frag-transpose (unchanged) ----------------
__global__ __launch_bounds__(1024) void prep_kernel(
    const float* __restrict__ q, const float* __restrict__ k, const float* __restrict__ v,
    const float* __restrict__ igk, const float* __restrict__ igb,
    const float* __restrict__ fgk, const float* __restrict__ fgb,
    float* __restrict__ ig_out, float* __restrict__ fg_out,
    _Float16* __restrict__ Qh, _Float16* __restrict__ Kh, _Float16* __restrict__ Vt)
{
    __shared__ __align__(16) char PSM[98304];
    char* wiB = PSM;            // 48 KB, swizzled float4 per element
    char* wfB = PSM + 49152;

    const int t = threadIdx.x;
    #pragma unroll
    for (int i = 0; i < 3; ++i) {
        int e = t + 1024 * i;
        *(float4*)(wiB + wofs(e)) = ((const float4*)igk)[e];
        *(float4*)(wfB + wofs(e)) = ((const float4*)fgk)[e];
    }
    __syncthreads();

    const int wave = t >> 6;
    const int l    = t & 63;
    const int bs   = blockIdx.x * 16 + wave;     // b*S + s
    const int b = bs >> 11, s = bs & (S_ - 1);
    const float* qrow = q + (size_t)bs * E_;
    const float* krow = k + (size_t)bs * E_;
    const float* vrow = v + (size_t)bs * E_;

    float accI[4] = {0.f,0.f,0.f,0.f}, accF[4] = {0.f,0.f,0.f,0.f};
    #pragma unroll
    for (int j = 0; j < 12; ++j) {
        const int e4 = l * 4 + 256 * j;          // 4 consecutive elements of gate_in
        float4 g4;
        if (j < 4)       g4 = *(const float4*)(qrow + e4);
        else if (j < 8)  g4 = *(const float4*)(krow + (e4 - E_));
        else             g4 = *(const float4*)(vrow + (e4 - 2 * E_));
        const float ge[4] = {g4.x, g4.y, g4.z, g4.w};
        if (j < 4) {
            const int d = e4 & 255, hh = e4 >> 8;
            const int idx = ((s >> 4) * 8 + (d >> 5)) * 512
                          + (s & 15) * 8 + (((d & 31) >> 3) << 7) + (d & 7);
            half4v st;
            st.x = (_Float16)(ge[0] * 0.0625f); st.y = (_Float16)(ge[1] * 0.0625f);
            st.z = (_Float16)(ge[2] * 0.0625f); st.w = (_Float16)(ge[3] * 0.0625f);
            *(half4v*)(Qh + ((size_t)(b * NH_ + hh)) * (S_ * HD_) + idx) = st;
        } else if (j < 8) {
            const int e2 = e4 - E_;
            const int d = e2 & 255, hh = e2 >> 8;
            const int idx = ((s >> 4) * 8 + (d >> 5)) * 512
                          + (s & 15) * 8 + (((d & 31) >> 3) << 7) + (d & 7);
            half4v st;
            st.x = (_Float16)ge[0]; st.y = (_Float16)ge[1];
            st.z = (_Float16)ge[2]; st.w = (_Float16)ge[3];
            *(half4v*)(Kh + ((size_t)(b * NH_ + hh)) * (S_ * HD_) + idx) = st;
        }
        #pragma unroll
        for (int i = 0; i < 4; ++i) {
            float4 wiv = *(const float4*)(wiB + wofs(e4 + i));
            float4 wfv = *(const float4*)(wfB + wofs(e4 + i));
            accI[0] = fmaf(ge[i], wiv.x, accI[0]); accI[1] = fmaf(ge[i], wiv.y, accI[1]);
            accI[2] = fmaf(ge[i], wiv.z, accI[2]); accI[3] = fmaf(ge[i], wiv.w, accI[3]);
            accF[0] = fmaf(ge[i], wfv.x, accF[0]); accF[1] = fmaf(ge[i], wfv.y, accF[1]);
            accF[2] = fmaf(ge[i], wfv.z, accF[2]); accF[3] = fmaf(ge[i], wfv.w, accF[3]);
        }
    }
    #pragma unroll
    for (int m = 1; m < 64; m <<= 1) {
        #pragma unroll
        for (int h = 0; h < 4; ++h) {
            accI[h] += __shfl_xor(accI[h], m);
            accF[h] += __shfl_xor(accF[h], m);
        }
    }
    if (l == 0) {
        #pragma unroll
        for (int h = 0; h < 4; ++h) {
            ig_out[((size_t)(b * NH_ + h)) * S_ + s] = accI[h] + igb[h];
            fg_out[((size_t)(b * NH_ + h)) * S_ + s] = accF[h] + fgb[h];
        }
    }

    __syncthreads();    // all weight reads done; reuse LDS for V transpose
    {
        float (*tile)[65] = (float(*)[65])(PSM + (t >> 8) * 16640);
        const int tid = t & 255;
        const int m  = blockIdx.x * 4 + (t >> 8);    // 0..1023 tile jobs
        const int bh = m & 7;
        const int sb = (m >> 3) & 31;                // ktile
        const int db = m >> 8;                       // d block of 64
        const int bb = bh >> 2, hh = bh & 3;
        const int j4 = (tid & 15) * 4;
        const int i0 = tid >> 4;
        const float* src = v + ((size_t)(bb * S_ + sb * 64)) * E_ + hh * HD_ + db * 64;
        #pragma unroll
        for (int p = 0; p < 4; ++p) {
            int i = i0 + p * 16;
            float4 val = *(const float4*)(src + (size_t)i * E_ + j4);
            tile[i][j4] = val.x; tile[i][j4+1] = val.y; tile[i][j4+2] = val.z; tile[i][j4+3] = val.w;
        }
        __syncthreads();
        const int ll = tid & 63;
        const int sw_ = tid >> 6;
        _Float16* dstb = Vt + (size_t)bh * (S_ * HD_);
        #pragma unroll
        for (int kb = 0; kb < 2; ++kb) {
            half8 pk;
            #pragma unroll
            for (int jj = 0; jj < 8; ++jj)
                pk[jj] = (_Float16)tile[kb * 32 + (ll >> 4) * 8 + jj][sw_ * 16 + (ll & 15)];
            *(half8*)(dstb + ((size_t)((sb * 16 + db * 4 + sw_) * 2 + kb)) * 512 + ll * 8) = pk;
        }
    }
}

// ---------------- Kernel 2 (R9): async global_load_lds V staging + counted vmcnt ----------------
// R8 post-mortem: 1024-thr blocks cap unified regs at 128 (split ~64 arch) -> spills (2nd
// time; R2 identical). Wave-count levers are register-blocked.
// R9 = R7 + register-free TA feeding: V staged via global_load_lds (async DMA, 0 VGPR,
// issued in the PV region) into a 2x64KB LDS dbuf; the per-tile barrier uses COUNTED
// vmcnt(8): the only non-V outstanding vmem is the 8 kf refills, so vmcnt(8) proves all
// V(j) DMA writes landed while kf(j+1) stays in flight (vmcnt(0) on the final masked tile
// where there is no refill). Frees vf's 32 VGPRs (kills R7's residual scratch). LDS 155KB:
// sAmM/sM shrink to this block's 64 rows (only sG needs all of S).
static constexpr int OFF_PB = 131072;                  // Vlds [2][64 KB] at 0
static constexpr int OFF_G  = OFF_PB + 16384;          // P dbuf [2][32 rows][256 B]
static constexpr int OFF_A2 = OFF_G + S_ * 4;          // sG [S]
static constexpr int OFF_M2 = OFF_A2 + 256;            // amM2 [64]
static constexpr int OFF_RS = OFF_M2 + 256;            // sM2 [64]
static constexpr int OFF_SS = OFF_RS + 1024;           // rsumP [8][32]
static constexpr int OFF_WR = OFF_SS + 1024;           // ssP [8][32]
static constexpr int SMB    = OFF_WR + 128;            // 158336 B (<160 KiB)

#define TILE_BODY(MASKED)                                                     \
{                                                                             \
    /* swapped QK^T: D[k][q] from kf+qf regs */                               \
    f32x4 s0 = (f32x4){0.f,0.f,0.f,0.f}, s1 = (f32x4){0.f,0.f,0.f,0.f};      \
    __builtin_amdgcn_s_setprio(1);                                            \
    _Pragma("unroll")                                                         \
    for (int kk = 0; kk < 8; ++kk) {                                          \
        s0 = __builtin_amdgcn_mfma_f32_16x16x32_f16(kf[kk], qf0[kk], s0, 0, 0, 0); \
        s1 = __builtin_amdgcn_mfma_f32_16x16x32_f16(kf[kk], qf1[kk], s1, 0, 0, 0); \
    }                                                                         \
    __builtin_amdgcn_s_setprio(0);                                            \
    if (!MASKED) {  /* kf refill for next tile; stays in flight across barrier */ \
        const _Float16* kb_ = Kp + ((size_t)((jt + 1) * 8 + w) * 8) * 512 + l * 8; \
        _Pragma("unroll")                                                     \
        for (int kk = 0; kk < 8; ++kk) kf[kk] = *(const half8*)(kb_ + kk * 512); \
    }                                                                         \
    /* fixup: p = s * exp2(amM[q] + G2[k]); mask only on diagonal tile */     \
    {                                                                         \
        float4 gv4 = *(const float4*)(sG + jt * 128 + w * 16 + quad * 4);     \
        const float gvv[4] = {gv4.x, gv4.y, gv4.z, gv4.w};                    \
        char* pbC = Pb + (jt & 1) * 8192;                                     \
        half4v h0, h1;                                                        \
        _Pragma("unroll")                                                     \
        for (int rr = 0; rr < 4; ++rr) {                                      \
            float p0 = s0[rr] * __builtin_amdgcn_exp2f(amM0 + gvv[rr]);       \
            float p1 = s1[rr] * __builtin_amdgcn_exp2f(amM1 + gvv[rr]);       \
            if (MASKED) {                                                     \
                const int gc = jt * 128 + w * 16 + quad * 4 + rr;             \
                p0 = (gc <= rowbase + col) ? p0 : 0.f;                        \
                p1 = (gc <= rowbase + 16 + col) ? p1 : 0.f;                   \
            }                                                                 \
            rs0 += p0; rs1 += p1;                                             \
            h0[rr] = (_Float16)p0; h1[rr] = (_Float16)p1;                     \
        }                                                                     \
        const int wb = (w * 32 + quad * 8) ^ ((col & 7) << 4);                \
        *(half4v*)(pbC + col * 256 + wb) = h0;                                \
        *(half4v*)(pbC + (16 + col) * 256 + wb) = h1;                         \
    }                                                                         \
    /* counted-vmcnt barrier: forces all V(jt) DMA writes + P visible;        \
       non-V outstanding = 8 kf refills exactly, so vmcnt(8) is sufficient    \
       and leaves kf in flight. Final tile has no refill -> vmcnt(0). */      \
    if (MASKED) { asm volatile("s_waitcnt vmcnt(0) lgkmcnt(0)" ::: "memory"); } \
    else        { asm volatile("s_waitcnt vmcnt(8) lgkmcnt(0)" ::: "memory"); } \
    __builtin_amdgcn_s_barrier();                                             \
    /* PV: P (swizzled) + V (linear) both from LDS */                         \
    {                                                                         \
        const char* pbC = Pb + (jt & 1) * 8192;                               \
        const char* vbC = Vlds + (jt & 1) * 65536;                            \
        const int sw2 = (col & 7) << 4;                                       \
        half8 vv[8];                                                          \
        _Pragma("unroll")                                                     \
        for (int dn = 0; dn < 2; ++dn) {                                      \
            _Pragma("unroll")                                                 \
            for (int k0 = 0; k0 < 4; ++k0)                                    \
                vv[dn * 4 + k0] = *(const half8*)(vbC                         \
                    + ((((k0 >> 1) * 16 + w * 2 + dn) * 2 + (k0 & 1)) * 1024) + l * 16); \
        }                                                                     \
        __builtin_amdgcn_s_setprio(1);                                        \
        _Pragma("unroll")                                                     \
        for (int rsub = 0; rsub < 2; ++rsub) {                                \
            const char* base = pbC + (rsub * 16 + col) * 256;                 \
            half8 af[4];                                                      \
            _Pragma("unroll")                                                 \
            for (int k0 = 0; k0 < 4; ++k0)                                    \
                af[k0] = *(const half8*)(base + ((k0 * 64 + quad * 16) ^ sw2)); \
            _Pragma("unroll")                                                 \
            for (int k0 = 0; k0 < 4; ++k0) {                                  \
                acc[rsub * 2 + 0] = __builtin_amdgcn_mfma_f32_16x16x32_f16(af[k0], vv[k0],     acc[rsub * 2 + 0], 0, 0, 0); \
                acc[rsub * 2 + 1] = __builtin_amdgcn_mfma_f32_16x16x32_f16(af[k0], vv[4 + k0], acc[rsub * 2 + 1], 0, 0, 0); \
            }                                                                 \
        }                                                                     \
        __builtin_amdgcn_s_setprio(0);                                        \
    }                                                                         \
    if (!MASKED) VSTAGE(jt + 1);   /* async DMA for next tile, overlaps next QK */ \
}

__global__ __launch_bounds__(512, 2) void mlstm_kernel(
    const _Float16* __restrict__ Qh, const _Float16* __restrict__ Kh,
    const _Float16* __restrict__ Vt,
    const float* __restrict__ ig, const float* __restrict__ fg,
    const float* __restrict__ rms_scale, float* __restrict__ out)
{
    __shared__ __align__(16) char SMEM[SMB];
    char*  Vlds  = SMEM;                             // [2][65536] V tile dbuf (DMA dest)
    char*  Pb    = SMEM + OFF_PB;                    // [2][32][256 B] halfs, swizzled
    float* sG    = (float*)(SMEM + OFF_G);           // [S]  g*log2e
    float* amM2  = (float*)(SMEM + OFF_A2);          // [64] (A-M)*log2e, own rows only
    float* sM2   = (float*)(SMEM + OFF_M2);          // [64] M, own rows only
    float* rsumP = (float*)(SMEM + OFF_RS);          // [8][32]
    float* ssP   = (float*)(SMEM + OFF_SS);          // [8][32]
    float* wred  = (float*)(SMEM + OFF_WR);          // [8]
    float* wred2 = wred + 8;                         // [8]

    const int z  = blockIdx.x;
    const int bh = z & 7;                 // one head per XCD
    const int u  = z >> 3;                // 0..31; block owns row-blocks {u, 63-u}
    const int b  = bh >> 2, h = bh & 3;
    const int t  = threadIdx.x;
    const int w  = t >> 6;                // 0..7: QK k-group (16) / PV d-slice (32)
    const int l  = t & 63;
    const int col  = l & 15;
    const int quad = l >> 4;
    constexpr float LOG2E = 1.4426950408889634f;

    // ---- scan prologue: wave-level shfl scans; sG full, AmM/M compact (own 64 rows) ----
    {
        const float* fgp = fg + (size_t)bh * S_;
        const float* igp = ig + (size_t)bh * S_;
        float4 fx = *(const float4*)(fgp + t * 4);
        float4 ix = *(const float4*)(igp + t * 4);
        float xi[4] = {fx.x, fx.y, fx.z, fx.w};
        float gi[4] = {ix.x, ix.y, ix.z, ix.w};
        float ls[4];
        float run = 0.f;
        #pragma unroll
        for (int i = 0; i < 4; ++i) {
            float x = xi[i];
            float lg = (x >= 0.f) ? -log1pf(expf(-x)) : (x - log1pf(expf(x)));
            run += lg;
            ls[i] = run;
        }
        const float own = run;
        #pragma unroll
        for (int m = 1; m < 64; m <<= 1) {
            float o = __shfl_up(run, m);
            if (l >= m) run += o;
        }
        if (l == 63) wred[w] = run;
        __syncthreads();
        float wpre = 0.f;
        for (int ww = 0; ww < w; ++ww) wpre += wred[ww];
        const float exclT = wpre + run - own;
        float A[4], g[4], gm[4];
        float rmax = -__builtin_inff();
        #pragma unroll
        for (int i = 0; i < 4; ++i) {
            A[i] = exclT + ls[i];
            g[i] = gi[i] - A[i];
            rmax = fmaxf(rmax, g[i]);
            gm[i] = rmax;
        }
        float sm = rmax;
        #pragma unroll
        for (int m = 1; m < 64; m <<= 1) {
            float o = __shfl_up(sm, m);
            if (l >= m) sm = fmaxf(sm, o);
        }
        if (l == 63) wred2[w] = sm;
        __syncthreads();
        float exm = -__builtin_inff();
        for (int ww = 0; ww < w; ++ww) exm = fmaxf(exm, wred2[ww]);
        float up = __shfl_up(sm, 1);
        if (l > 0) exm = fmaxf(exm, up);
        #pragma unroll
        for (int i = 0; i < 4; ++i) {
            float cm = fmaxf(exm, gm[i]);
            float Mi = A[i] + cm;
            const int r = t * 4 + i;
            sG[r] = g[i] * LOG2E;
            const int rb5 = r >> 5;
            int slot = (rb5 == u) ? (r & 31) : ((rb5 == 63 - u) ? 32 + (r & 31) : -1);
            if (slot >= 0) {
                amM2[slot] = (A[i] - Mi) * LOG2E;
                sM2[slot]  = Mi;
            }
        }
        __syncthreads();
    }

    const _Float16* Qp  = Qh + (size_t)bh * S_ * HD_;
    const _Float16* Kp  = Kh + (size_t)bh * S_ * HD_;
    const _Float16* Vtp = Vt + (size_t)bh * HD_ * S_;

    half8 kf[8];

    // async stage of one V tile (64 KB = 64 fragments); wave w stages frags w*8..w*8+7.
    // LDS dest is wave-uniform + lane*16 (linear), global src is per-lane: layout match.
    auto VSTAGE = [&](int tile) {
        char* dst = Vlds + (tile & 1) * 65536 + w * 8192;
        const _Float16* src = Vtp + (size_t)tile * 32768 + w * 4096 + l * 8;
        #pragma unroll
        for (int f = 0; f < 8; ++f)
            __builtin_amdgcn_global_load_lds(
                (const __attribute__((address_space(1))) void*)(src + f * 512),
                (__attribute__((address_space(3))) void*)(dst + f * 1024), 16, 0, 0);
    };

    for (int pass = 0; pass < 2; ++pass) {
        const int rb = pass ? (63 - u) : u;
        const int rowbase = rb * 32;
        const int Tt = (rb >> 2) + 1;          // KVBLK=128 causal tile count

        // Q fragments: both 16-row halves (64 VGPR), reused across all tiles
        half8 qf0[8], qf1[8];
        {
            const _Float16* qb0 = Qp + ((size_t)(rb * 2) * 8) * 512 + l * 8;
            const _Float16* qb1 = Qp + ((size_t)(rb * 2 + 1) * 8) * 512 + l * 8;
            #pragma unroll
            for (int kk = 0; kk < 8; ++kk) {
                qf0[kk] = *(const half8*)(qb0 + kk * 512);
                qf1[kk] = *(const half8*)(qb1 + kk * 512);
            }
        }
        const float amM0 = amM2[pass * 32 + col];
        const float amM1 = amM2[pass * 32 + 16 + col];

        f32x4 acc[4];
        #pragma unroll
        for (int i = 0; i < 4; ++i) acc[i] = (f32x4){0.f, 0.f, 0.f, 0.f};
        float rs0 = 0.f, rs1 = 0.f;

        // preload tile-0 K (regs) then tile-0 V (async DMA)
        {
            const _Float16* kb_ = Kp + ((size_t)(w * 8)) * 512 + l * 8;
            #pragma unroll
            for (int kk = 0; kk < 8; ++kk)
                kf[kk] = *(const half8*)(kb_ + kk * 512);
        }
        VSTAGE(0);

        int jt = 0;
        for (; jt + 1 < Tt; ++jt) { TILE_BODY(false); }
        TILE_BODY(true);

        // ---- epilogue: rowsum across 8 k-waves, normalize, RMSNorm, store d-slice ----
        rs0 += __shfl_xor(rs0, 16); rs0 += __shfl_xor(rs0, 32);
        rs1 += __shfl_xor(rs1, 16); rs1 += __shfl_xor(rs1, 32);
        if (quad == 0) {
            rsumP[w * 32 + col]      = rs0;
            rsumP[w * 32 + 16 + col] = rs1;
        }
        __syncthreads();
        float inv0[4], inv1[4];
        #pragma unroll
        for (int rr = 0; rr < 4; ++rr) {
            const int r0 = quad * 4 + rr;
            float tot0 = 0.f, tot1 = 0.f;
            #pragma unroll
            for (int ww = 0; ww < 8; ++ww) {
                tot0 += rsumP[ww * 32 + r0];
                tot1 += rsumP[ww * 32 + 16 + r0];
            }
            float M0 = sM2[pass * 32 + r0];
            float M1 = sM2[pass * 32 + 16 + r0];
            inv0[rr] = 1.0f / (fmaxf(tot0, __expf(-M0)) + 1e-6f);
            inv1[rr] = 1.0f / (fmaxf(tot1, __expf(-M1)) + 1e-6f);
        }
        float ss0[4] = {0.f,0.f,0.f,0.f}, ss1[4] = {0.f,0.f,0.f,0.f};
        #pragma unroll
        for (int dn = 0; dn < 2; ++dn) {
            #pragma unroll
            for (int rr = 0; rr < 4; ++rr) {
                float h0 = acc[dn][rr] * inv0[rr];
                acc[dn][rr] = h0;
                ss0[rr] = fmaf(h0, h0, ss0[rr]);
                float h1 = acc[2 + dn][rr] * inv1[rr];
                acc[2 + dn][rr] = h1;
                ss1[rr] = fmaf(h1, h1, ss1[rr]);
            }
        }
        #pragma unroll
        for (int m = 1; m < 16; m <<= 1) {
            #pragma unroll
            for (int rr = 0; rr < 4; ++rr) {
                ss0[rr] += __shfl_xor(ss0[rr], m);
                ss1[rr] += __shfl_xor(ss1[rr], m);
            }
        }
        if (col == 0) {
            #pragma unroll
            for (int rr = 0; rr < 4; ++rr) {
                ssP[w * 32 + quad * 4 + rr]      = ss0[rr];
                ssP[w * 32 + 16 + quad * 4 + rr] = ss1[rr];
            }
        }
        __syncthreads();
        const float rsc0 = 1.f + rms_scale[w * 32 + col];
        const float rsc1 = 1.f + rms_scale[w * 32 + 16 + col];
        #pragma unroll
        for (int rr = 0; rr < 4; ++rr) {
            const int r0 = quad * 4 + rr;
            float sst0 = 0.f, sst1 = 0.f;
            #pragma unroll
            for (int ww = 0; ww < 8; ++ww) {
                sst0 += ssP[ww * 32 + r0];
                sst1 += ssP[ww * 32 + 16 + r0];
            }
            float rstd0 = rsqrtf(sst0 * (1.0f / HD_) + 1e-6f);
            float rstd1 = rsqrtf(sst1 * (1.0f / HD_) + 1e-6f);
            float* o0 = out + ((size_t)(b * S_ + rowbase + r0)) * E_ + h * HD_ + w * 32;
            float* o1 = out + ((size_t)(b * S_ + rowbase + 16 + r0)) * E_ + h * HD_ + w * 32;
            o0[col]      = acc[0][rr] * rstd0 * rsc0;
            o0[16 + col] = acc[1][rr] * rstd0 * rsc1;
            o1[col]      = acc[2][rr] * rstd1 * rsc0;
            o1[16 + col] = acc[3][rr] * rstd1 * rsc1;
        }
        __syncthreads();   // rsumP/ssP/Vlds retired before next pass restages
    }
}

extern "C" void kernel_launch(void* const* d_in, const int* in_sizes, int n_in,
                              void* d_out, int out_size, void* d_ws, size_t ws_size,
                              hipStream_t stream) {
    (void)in_sizes; (void)n_in; (void)out_size; (void)ws_size;
    const float* q   = (const float*)d_in[0];
    const float* k   = (const float*)d_in[1];
    const float* v   = (const float*)d_in[2];
    const float* igk = (const float*)d_in[3];
    const float* igb = (const float*)d_in[4];
    const float* fgk = (const float*)d_in[5];
    const float* fgb = (const float*)d_in[6];
    const float* rsc = (const float*)d_in[7];
    float* out = (float*)d_out;

    float* ws  = (float*)d_ws;
    float* ig  = ws;                          // BH*S each
    float* fg  = ws + (size_t)BH_ * S_;
    _Float16* Qh = (_Float16*)(ws + (size_t)2 * BH_ * S_);
    _Float16* Kh = Qh + (size_t)BH_ * S_ * HD_;
    _Float16* Vt = Kh + (size_t)BH_ * S_ * HD_;

    prep_kernel<<<B_ * S_ / 16, 1024, 0, stream>>>(q, k, v, igk, igb, fgk, fgb,
                                                   ig, fg, Qh, Kh, Vt);
    mlstm_kernel<<<BH_ * 32, 512, 0, stream>>>(Qh, Kh, Vt, ig, fg, rsc, out);
}